// Round 6
// baseline (238.484 us; speedup 1.0000x reference)
//
#include <hip/hip_runtime.h>
#include <hip/hip_bf16.h>
#include <stdint.h>

typedef _Float16 f16;
typedef __attribute__((ext_vector_type(8))) _Float16 f16x8;
typedef __attribute__((ext_vector_type(4))) float f32x4;

#define M_DIM 2048    // B*S multivector rows
#define K_FULL 8192   // IN*32 (fallback path)
#define M2 8192       // M_DIM*4   (GEMM rows: (m,c))
#define K2 2048       // IN*8      (GEMM K: (i,t,p))
#define N2 2048       // OUT*8     (GEMM cols: (o,r,q))
// 256x256x64 tile, 8 waves (2x4), 1 block/CU; A-only LDS double buffer 64 KiB
#define BM 256
#define BN 256
#define BK 64
#define NT (K2 / BK)  // 32 K-tiles
#define PSTR 260      // epilogue LDS stride (floats)

// ================= compile-time Cl(4,1) -> M(4,C) tables =================
struct CMat { int re[4][4]; int im[4][4]; };

constexpr CMat cmul(const CMat& A, const CMat& B) {
  CMat C{};
  for (int r = 0; r < 4; ++r)
    for (int c = 0; c < 4; ++c) {
      int re = 0, im = 0;
      for (int t = 0; t < 4; ++t) {
        re += A.re[r][t] * B.re[t][c] - A.im[r][t] * B.im[t][c];
        im += A.re[r][t] * B.im[t][c] + A.im[r][t] * B.re[t][c];
      }
      C.re[r][c] = re; C.im[r][c] = im;
    }
  return C;
}

constexpr int gp_sign_ct(int a, int b) {
  int sw = 0;
  for (int t = a >> 1; t; t >>= 1) {
    int x = t & b;
    while (x) { sw += x & 1; x >>= 1; }
  }
  int s = (sw & 1) ? -1 : 1;
  if ((a & b) & 16) s = -s;   // e5^2 = -1
  return s;
}

struct Tables {
  int8_t f_idx[32][4]; int8_t f_sgn[32][4];  // slot -> 4 (blade, sign)
  int8_t g_idx[32][4]; int8_t g_sgn[32][4];  // blade -> 4 (slot, sign)
  bool ok;
};

constexpr Tables make_tables() {
  CMat G[5] = {
    { {{0,0,0,1},{0,0,1,0},{0,1,0,0},{1,0,0,0}},
      {{0,0,0,0},{0,0,0,0},{0,0,0,0},{0,0,0,0}} },
    { {{0,0,0,0},{0,0,0,0},{0,0,0,0},{0,0,0,0}},
      {{0,0,0,-1},{0,0,1,0},{0,-1,0,0},{1,0,0,0}} },
    { {{0,0,1,0},{0,0,0,-1},{1,0,0,0},{0,-1,0,0}},
      {{0,0,0,0},{0,0,0,0},{0,0,0,0},{0,0,0,0}} },
    { {{0,0,0,0},{0,0,0,0},{0,0,0,0},{0,0,0,0}},
      {{0,0,-1,0},{0,0,0,-1},{1,0,0,0},{0,1,0,0}} },
    { {{0,0,0,0},{0,0,0,0},{0,0,0,0},{0,0,0,0}},
      {{1,0,0,0},{0,1,0,0},{0,0,-1,0},{0,0,0,-1}} } };
  CMat ID{ {{1,0,0,0},{0,1,0,0},{0,0,1,0},{0,0,0,1}},
           {{0,0,0,0},{0,0,0,0},{0,0,0,0},{0,0,0,0}} };
  CMat U[32] = {};
  for (int A = 0; A < 32; ++A) {
    CMat u = ID;
    for (int b = 0; b < 5; ++b) if (A & (1 << b)) u = cmul(u, G[b]);
    U[A] = u;
  }
  bool ok = true;
  for (int a = 0; a < 32; ++a)
    for (int b = 0; b < 32; ++b) {
      CMat P = cmul(U[a], U[b]);
      int s = gp_sign_ct(a, b);
      const CMat& T = U[a ^ b];
      for (int r = 0; r < 4; ++r)
        for (int c = 0; c < 4; ++c)
          if (P.re[r][c] != s * T.re[r][c] || P.im[r][c] != s * T.im[r][c]) ok = false;
    }
  Tables t{};
  int cnt[32] = {};
  for (int A = 0; A < 32; ++A) {
    int n = 0;
    for (int r = 0; r < 4; ++r)
      for (int c = 0; c < 4; ++c) {
        int vr = U[A].re[r][c], vi = U[A].im[r][c];
        if (vr) {
          int s = (r * 4 + c) * 2;
          if (n < 4 && cnt[s] < 4) {
            t.g_idx[A][n] = (int8_t)s; t.g_sgn[A][n] = (int8_t)vr;
            t.f_idx[s][cnt[s]] = (int8_t)A; t.f_sgn[s][cnt[s]] = (int8_t)vr;
            cnt[s]++;
          } else ok = false;
          n++;
        }
        if (vi) {
          int s = (r * 4 + c) * 2 + 1;
          if (n < 4 && cnt[s] < 4) {
            t.g_idx[A][n] = (int8_t)s; t.g_sgn[A][n] = (int8_t)vi;
            t.f_idx[s][cnt[s]] = (int8_t)A; t.f_sgn[s][cnt[s]] = (int8_t)vi;
            cnt[s]++;
          } else ok = false;
          n++;
        }
      }
    if (n != 4) ok = false;
  }
  for (int s = 0; s < 32; ++s) if (cnt[s] != 4) ok = false;
  t.ok = ok;
  return t;
}

constexpr Tables HT = make_tables();
static_assert(HT.ok, "Cl(4,1) -> M(4,C) homomorphism check FAILED");
static_assert((NT & 1) == 0, "buffer parity requires even tile count");

__device__ __forceinline__ void async16(const f16* g, f16* l) {
  __builtin_amdgcn_global_load_lds(
      (const __attribute__((address_space(1))) uint32_t*)g,
      (__attribute__((address_space(3))) uint32_t*)l,
      16, 0, 0);
}

__device__ __forceinline__ float gp_sign_rt(int a, int b) {
  int sw = 0;
  for (int t = a >> 1; t; t >>= 1) sw += __popc(t & b);
  float s = (sw & 1) ? -1.0f : 1.0f;
  if ((a & b) & 16) s = -s;
  return s;
}

#define FENCE() asm volatile("" ::: "memory")
#define BARRIER() do { FENCE(); __builtin_amdgcn_s_barrier(); FENCE(); } while (0)
#define WAIT_VM(N) asm volatile("s_waitcnt vmcnt(" #N ")" ::: "memory")

// ---- fused forward transforms (x -> Ag, w -> Bt), LDS-coalesced ----
// blocks [0,2048): x rows; blocks [2048,2304): w rows.
__global__ __launch_bounds__(256) void fwd_kernel(const float* __restrict__ x,
                                                  const float* __restrict__ w,
                                                  f16* __restrict__ Ag,
                                                  f16* __restrict__ Bt) {
  __shared__ float xs[256 * 33];
  const int b = blockIdx.x, t = threadIdx.x;
  const bool isx = (b < M_DIM);
  const float* src0 = isx ? (x + (size_t)b * 8192)
                          : (w + (size_t)(b - M_DIM) * 8192);
  const float4* src = (const float4*)src0;
#pragma unroll
  for (int c = t; c < 2048; c += 256) {      // fully coalesced 16B loads
    float4 v = src[c];
    float* d = xs + (c >> 3) * 33 + ((c & 7) << 2);
    d[0] = v.x; d[1] = v.y; d[2] = v.z; d[3] = v.w;
  }
  __syncthreads();
  const float* xv = xs + t * 33;             // bank = (t+e)%32: conflict-free
  float sv[32];
#pragma unroll
  for (int s = 0; s < 32; ++s)
    sv[s] = (float)HT.f_sgn[s][0] * xv[HT.f_idx[s][0]]
          + (float)HT.f_sgn[s][1] * xv[HT.f_idx[s][1]]
          + (float)HT.f_sgn[s][2] * xv[HT.f_idx[s][2]]
          + (float)HT.f_sgn[s][3] * xv[HT.f_idx[s][3]];
  if (isx) {
#pragma unroll
    for (int c = 0; c < 4; ++c) {
      f16x8 h;
#pragma unroll
      for (int e = 0; e < 8; ++e) {   // e = tt*2+p -> slot tt*8+c*2+p
        int tt = e >> 1, p = e & 1;
        h[e] = (f16)sv[tt * 8 + c * 2 + p];
      }
      *(f16x8*)(Ag + ((size_t)(b * 4 + c)) * K2 + t * 8) = h;
    }
  } else {
    const int o = b - M_DIM;
#pragma unroll
    for (int r = 0; r < 4; ++r)
#pragma unroll
      for (int q = 0; q < 2; ++q) {
        f16x8 h;
#pragma unroll
        for (int e = 0; e < 8; ++e) {
          int tt = e >> 1, p = e & 1;
          float re = sv[(r * 4 + tt) * 2], im = sv[(r * 4 + tt) * 2 + 1];
          float v = (q == 0) ? (p == 0 ? re : -im) : (p == 0 ? im : re);
          h[e] = (f16)v;
        }
        *(f16x8*)(Bt + ((size_t)(o * 8 + r * 2 + q)) * K2 + t * 8) = h;
      }
  }
}

// ---- fused GEMM + inverse transform + normalize ----
// LDS-load surgery: B fragments are read DIRECTLY global->VGPR (Bt is K-major,
// each frag = 16 contiguous bytes; B panels are L2-hot across 32 blocks/XCD and
// each 128B line serves 8 frag reads via L1). This removes 8 of 24 ds_reads per
// wave per tile AND all B staging — LDS becomes a single 64 KiB A double-buffer.
// vmcnt discipline: bv loads issue FIRST (oldest), A-stages after a fence
// (younger), so the compiler's counted bv waits do not drain the stages; one
// WAIT_VM(0) at tile end drains the 4 stages issued ~2 phases earlier (free).
__global__ __launch_bounds__(512, 2) void gemm_fused_kernel(const f16* __restrict__ A,
                                                            const f16* __restrict__ Bw,
                                                            float* __restrict__ out) {
  __shared__ __align__(16) char smem[66560];    // A dbuf 64K; epilogue 66.5K
  const int t = threadIdx.x;
  const int w = t >> 6, lane = t & 63;
  const int wr = w >> 2, wc = w & 3;            // 2x4 wave grid
  const int g = lane >> 4, lc = lane & 15;

  // XCD-aware swizzle: 256 blocks, 8 XCDs, 32-block contiguous chunk each
  const int bid = blockIdx.x;
  const int swzb = (bid & 7) * 32 + (bid >> 3);
  const int by = swzb >> 3, bx = swzb & 7;
  const int m0 = by * BM, n0 = bx * BN;

  // A staging: load j covers rows j*64 + w*8 + (lane>>3); stored chunk lane&7
  // holds global chunk (lane&7)^(row&7); LDS dest linear (global_load_lds).
  const int srow = lane >> 3;
  const int schk = (lane & 7) ^ srow;
  const f16* ga0 = A + (size_t)(m0 + w * 8 + srow) * K2 + schk * 8;
  const int lw = w << 10;                       // wave LDS byte base in j-block

  // A frag-read offsets: addr = base + row*128 + ((k2*4+g)^(lc&7))*16
  const int cks0 = (g ^ (lc & 7)) << 4;
  const int cks1 = ((4 | g) ^ (lc & 7)) << 4;
  const int arow = (wr << 14) + (lc << 7);      // wr band (128 rows)

  // B frag base: col = n0 + wc*64 + j*16 + lc, k-halves = u*64 + k2*32 + g*8
  const f16* gbf = Bw + (size_t)(n0 + (wc << 6) + lc) * K2 + (g << 3);

  f32x4 acc[8][4];
#pragma unroll
  for (int i = 0; i < 8; ++i)
#pragma unroll
    for (int j = 0; j < 4; ++j) {
      acc[i][j][0] = 0.f; acc[i][j][1] = 0.f; acc[i][j][2] = 0.f; acc[i][j][3] = 0.f;
    }

#define STG_A(NBO, KK, JB) async16(ga0 + (KK) + (JB) * 131072, \
                                   (f16*)(smem + (NBO) + (JB) * 8192 + lw))

  // prologue: stage tile 0 into buf0
  STG_A(0, 0, 0); STG_A(0, 0, 1); STG_A(0, 0, 2); STG_A(0, 0, 3);
  WAIT_VM(0);
  BARRIER();

  for (int u = 0; u < NT; ++u) {
    const int bo = (u & 1) << 15;
    const int nbo = bo ^ 32768;
    const int kn = (u + 1) * BK;
    const char* ab = smem + bo + arow;
    const bool stg = (u + 1 < NT);

    f16x8 av[4][2], bv[4][2];
    // ---- B frags from global (oldest vmem of this tile) ----
#pragma unroll
    for (int j = 0; j < 4; ++j) {
      bv[j][0] = *(const f16x8*)(gbf + (size_t)j * 32768 + u * 64);
      bv[j][1] = *(const f16x8*)(gbf + (size_t)j * 32768 + u * 64 + 32);
    }
    FENCE();   // pin: stages issue AFTER bv loads (keeps stages youngest)
    if (stg) { STG_A(nbo, kn, 0); STG_A(nbo, kn, 1);
               STG_A(nbo, kn, 2); STG_A(nbo, kn, 3); }

    // ---- P0: A rows 0-63 of the wr band ----
#pragma unroll
    for (int i = 0; i < 4; ++i) {
      av[i][0] = *(const f16x8*)(ab + i * 2048 + cks0);
      av[i][1] = *(const f16x8*)(ab + i * 2048 + cks1);
    }
    BARRIER();
    __builtin_amdgcn_s_setprio(1);
#pragma unroll
    for (int k2 = 0; k2 < 2; ++k2)
#pragma unroll
      for (int i = 0; i < 4; ++i)
#pragma unroll
        for (int j = 0; j < 4; ++j)
          acc[i][j] = __builtin_amdgcn_mfma_f32_16x16x32_f16(av[i][k2], bv[j][k2],
                                                             acc[i][j], 0, 0, 0);
    __builtin_amdgcn_s_setprio(0);
    BARRIER();

    // ---- P1: A rows 64-127 of the wr band ----
#pragma unroll
    for (int i = 0; i < 4; ++i) {
      av[i][0] = *(const f16x8*)(ab + (4 + i) * 2048 + cks0);
      av[i][1] = *(const f16x8*)(ab + (4 + i) * 2048 + cks1);
    }
    BARRIER();
    __builtin_amdgcn_s_setprio(1);
#pragma unroll
    for (int k2 = 0; k2 < 2; ++k2)
#pragma unroll
      for (int i = 0; i < 4; ++i)
#pragma unroll
        for (int j = 0; j < 4; ++j)
          acc[4 + i][j] = __builtin_amdgcn_mfma_f32_16x16x32_f16(av[i][k2], bv[j][k2],
                                                                 acc[4 + i][j], 0, 0, 0);
    __builtin_amdgcn_s_setprio(0);
    if (stg) WAIT_VM(0);   // drains the 4 stages issued ~2 phases ago: free
    BARRIER();
  }

#undef STG_A

  // ---- epilogue: four 64-row quarters through 66.5 KB LDS ----
  // C cell: A-row = wr*128 + I*16 + g*4 + r ; col = wc*64 + J*16 + lc
  float* ps = (float*)smem;
  __syncthreads();
#pragma unroll
  for (int qq = 0; qq < 4; ++qq) {
    if (qq) __syncthreads();
    if (wr == (qq >> 1)) {
      const int tb = (qq & 1) << 2;
#pragma unroll
      for (int tmi = 0; tmi < 4; ++tmi) {
        const int rowl = tmi * 16 + g * 4;
#pragma unroll
        for (int tn = 0; tn < 4; ++tn) {
          const int col = wc * 64 + tn * 16 + lc;
#pragma unroll
          for (int r = 0; r < 4; ++r)
            ps[(rowl + r) * PSTR + col] = acc[tb + tmi][tn][r];
        }
      }
    }
    __syncthreads();

    // 512 threads process 16 m-groups x 32 o-groups of this quarter
    const int mh = t >> 5, oh = t & 31;
    float yv[4][8];
#pragma unroll
    for (int c = 0; c < 4; ++c) {
      const float* row = ps + (mh * 4 + c) * PSTR + oh * 8;
      *(float4*)&yv[c][0] = *(const float4*)row;
      *(float4*)&yv[c][4] = *(const float4*)(row + 4);
    }
    float ss = 0.f;
#pragma unroll
    for (int c = 0; c < 4; ++c)
#pragma unroll
      for (int j = 0; j < 8; ++j) ss += yv[c][j] * yv[c][j];
    float inv = rsqrtf(0.25f * ss + 1e-6f);

    float ov[32];
#pragma unroll
    for (int k = 0; k < 32; ++k) {
      float v = 0.f;
#pragma unroll
      for (int j = 0; j < 4; ++j) {
        int s = HT.g_idx[k][j];       // compile-time constant after unroll
        int cell = s >> 1;
        int rr = cell >> 2, cc = cell & 3, pp = s & 1;
        float sgn = (float)HT.g_sgn[k][j];
        v += sgn * yv[cc][rr * 2 + pp];
      }
      ov[k] = v * 0.25f * inv;
    }
    int m = by * 64 + qq * 16 + mh;   // global multivector row
    int o = bx * 32 + oh;             // global output channel
    float* op = out + (size_t)m * 8192 + o * 32;
#pragma unroll
    for (int qv = 0; qv < 8; ++qv)
      *(float4*)(op + qv * 4) = make_float4(ov[qv * 4], ov[qv * 4 + 1],
                                            ov[qv * 4 + 2], ov[qv * 4 + 3]);
  }
}

// ---- safety-net fallback (ws too small): straight fp32 ----
__global__ __launch_bounds__(256) void naive_vl_kernel(const float* __restrict__ x,
                                                       const float* __restrict__ w,
                                                       float* __restrict__ out) {
  __shared__ float xs[8192];
  __shared__ float sgt[1024];
  int m = blockIdx.x, o0 = blockIdx.y << 3;
  int t = threadIdx.x;
  for (int i = t; i < 1024; i += 256) {
    int kk = i >> 5, ll = i & 31;
    sgt[i] = gp_sign_rt(kk ^ ll, ll);
  }
  const float4* xr = (const float4*)(x + (size_t)m * K_FULL);
  float4* xs4 = (float4*)xs;
  for (int i = t; i < 2048; i += 256) xs4[i] = xr[i];
  __syncthreads();
  int k = t & 31, ol = t >> 5;
  int o = o0 + ol;
  const float* wrow = w + (size_t)o * K_FULL;
  float acc = 0.f;
  for (int l = 0; l < 32; ++l) {
    float s = sgt[(k << 5) + l];
    const float* wp = wrow + (k ^ l);
    const float* xp = xs + l;
    float part = 0.f;
#pragma unroll 8
    for (int i = 0; i < 256; ++i) part += xp[i << 5] * wp[i << 5];
    acc += part * s;
  }
  float ss = acc * acc;
  for (int msk = 1; msk < 32; msk <<= 1) ss += __shfl_xor(ss, msk, 32);
  out[((size_t)m * 256 + o) * 32 + k] = acc * rsqrtf(ss + 1e-6f);
}

extern "C" void kernel_launch(void* const* d_in, const int* in_sizes, int n_in,
                              void* d_out, int out_size, void* d_ws, size_t ws_size,
                              hipStream_t stream) {
  const float* x = (const float*)d_in[0];
  const float* w = (const float*)d_in[1];
  float* out = (float*)d_out;

  size_t agE = (size_t)M2 * K2;        // 16.8M f16 = 33.5 MB
  size_t btE = (size_t)N2 * K2;        // 4.2M  f16 =  8.4 MB
  size_t need = (agE + btE) * sizeof(f16);  // ~42 MB

  if (ws_size >= need) {
    f16* Ag = (f16*)d_ws;
    f16* Bt = Ag + agE;
    fwd_kernel<<<dim3(M_DIM + 256), dim3(256), 0, stream>>>(x, w, Ag, Bt);
    gemm_fused_kernel<<<dim3((M2 / BM) * (N2 / BN)), dim3(512), 0, stream>>>(Ag, Bt, out);
  } else {
    naive_vl_kernel<<<dim3(M_DIM, 32), dim3(256), 0, stream>>>(x, w, out);
  }
}

// Round 7
// 188.779 us; speedup vs baseline: 1.2633x; 1.2633x over previous
//
#include <hip/hip_runtime.h>
#include <hip/hip_bf16.h>
#include <stdint.h>

typedef _Float16 f16;
typedef __attribute__((ext_vector_type(8))) _Float16 f16x8;
typedef __attribute__((ext_vector_type(4))) float f32x4;

#define M_DIM 2048    // B*S multivector rows
#define K_FULL 8192   // IN*32 (fallback path)
#define M2 8192       // M_DIM*4   (GEMM rows: (m,c))
#define K2 2048       // IN*8      (GEMM K: (i,t,p))
#define N2 2048       // OUT*8     (GEMM cols: (o,r,q))
// 256x256x64 tile, 8 waves (2x4), 1 block/CU, double-buffered 128 KiB LDS
#define BM 256
#define BN 256
#define BK 64
#define NT (K2 / BK)  // 32 K-tiles
#define PSTR 260      // epilogue LDS stride (floats)

// ================= compile-time Cl(4,1) -> M(4,C) tables =================
struct CMat { int re[4][4]; int im[4][4]; };

constexpr CMat cmul(const CMat& A, const CMat& B) {
  CMat C{};
  for (int r = 0; r < 4; ++r)
    for (int c = 0; c < 4; ++c) {
      int re = 0, im = 0;
      for (int t = 0; t < 4; ++t) {
        re += A.re[r][t] * B.re[t][c] - A.im[r][t] * B.im[t][c];
        im += A.re[r][t] * B.im[t][c] + A.im[r][t] * B.re[t][c];
      }
      C.re[r][c] = re; C.im[r][c] = im;
    }
  return C;
}

constexpr int gp_sign_ct(int a, int b) {
  int sw = 0;
  for (int t = a >> 1; t; t >>= 1) {
    int x = t & b;
    while (x) { sw += x & 1; x >>= 1; }
  }
  int s = (sw & 1) ? -1 : 1;
  if ((a & b) & 16) s = -s;   // e5^2 = -1
  return s;
}

struct Tables {
  int8_t f_idx[32][4]; int8_t f_sgn[32][4];  // slot -> 4 (blade, sign)
  int8_t g_idx[32][4]; int8_t g_sgn[32][4];  // blade -> 4 (slot, sign)
  bool ok;
};

constexpr Tables make_tables() {
  CMat G[5] = {
    { {{0,0,0,1},{0,0,1,0},{0,1,0,0},{1,0,0,0}},
      {{0,0,0,0},{0,0,0,0},{0,0,0,0},{0,0,0,0}} },
    { {{0,0,0,0},{0,0,0,0},{0,0,0,0},{0,0,0,0}},
      {{0,0,0,-1},{0,0,1,0},{0,-1,0,0},{1,0,0,0}} },
    { {{0,0,1,0},{0,0,0,-1},{1,0,0,0},{0,-1,0,0}},
      {{0,0,0,0},{0,0,0,0},{0,0,0,0},{0,0,0,0}} },
    { {{0,0,0,0},{0,0,0,0},{0,0,0,0},{0,0,0,0}},
      {{0,0,-1,0},{0,0,0,-1},{1,0,0,0},{0,1,0,0}} },
    { {{0,0,0,0},{0,0,0,0},{0,0,0,0},{0,0,0,0}},
      {{1,0,0,0},{0,1,0,0},{0,0,-1,0},{0,0,0,-1}} } };
  CMat ID{ {{1,0,0,0},{0,1,0,0},{0,0,1,0},{0,0,0,1}},
           {{0,0,0,0},{0,0,0,0},{0,0,0,0},{0,0,0,0}} };
  CMat U[32] = {};
  for (int A = 0; A < 32; ++A) {
    CMat u = ID;
    for (int b = 0; b < 5; ++b) if (A & (1 << b)) u = cmul(u, G[b]);
    U[A] = u;
  }
  bool ok = true;
  for (int a = 0; a < 32; ++a)
    for (int b = 0; b < 32; ++b) {
      CMat P = cmul(U[a], U[b]);
      int s = gp_sign_ct(a, b);
      const CMat& T = U[a ^ b];
      for (int r = 0; r < 4; ++r)
        for (int c = 0; c < 4; ++c)
          if (P.re[r][c] != s * T.re[r][c] || P.im[r][c] != s * T.im[r][c]) ok = false;
    }
  Tables t{};
  int cnt[32] = {};
  for (int A = 0; A < 32; ++A) {
    int n = 0;
    for (int r = 0; r < 4; ++r)
      for (int c = 0; c < 4; ++c) {
        int vr = U[A].re[r][c], vi = U[A].im[r][c];
        if (vr) {
          int s = (r * 4 + c) * 2;
          if (n < 4 && cnt[s] < 4) {
            t.g_idx[A][n] = (int8_t)s; t.g_sgn[A][n] = (int8_t)vr;
            t.f_idx[s][cnt[s]] = (int8_t)A; t.f_sgn[s][cnt[s]] = (int8_t)vr;
            cnt[s]++;
          } else ok = false;
          n++;
        }
        if (vi) {
          int s = (r * 4 + c) * 2 + 1;
          if (n < 4 && cnt[s] < 4) {
            t.g_idx[A][n] = (int8_t)s; t.g_sgn[A][n] = (int8_t)vi;
            t.f_idx[s][cnt[s]] = (int8_t)A; t.f_sgn[s][cnt[s]] = (int8_t)vi;
            cnt[s]++;
          } else ok = false;
          n++;
        }
      }
    if (n != 4) ok = false;
  }
  for (int s = 0; s < 32; ++s) if (cnt[s] != 4) ok = false;
  t.ok = ok;
  return t;
}

constexpr Tables HT = make_tables();
static_assert(HT.ok, "Cl(4,1) -> M(4,C) homomorphism check FAILED");
static_assert((NT & 1) == 0, "buffer parity requires even tile count");

__device__ __forceinline__ void async16(const f16* g, f16* l) {
  __builtin_amdgcn_global_load_lds(
      (const __attribute__((address_space(1))) uint32_t*)g,
      (__attribute__((address_space(3))) uint32_t*)l,
      16, 0, 0);
}

__device__ __forceinline__ float gp_sign_rt(int a, int b) {
  int sw = 0;
  for (int t = a >> 1; t; t >>= 1) sw += __popc(t & b);
  float s = (sw & 1) ? -1.0f : 1.0f;
  if ((a & b) & 16) s = -s;
  return s;
}

#define FENCE() asm volatile("" ::: "memory")
#define BARRIER() do { FENCE(); __builtin_amdgcn_s_barrier(); FENCE(); } while (0)
#define WAIT_VM(N) asm volatile("s_waitcnt vmcnt(" #N ")" ::: "memory")

// ---- fused forward transforms (x -> Ag, w -> Bt), LDS-coalesced ----
__global__ __launch_bounds__(256) void fwd_kernel(const float* __restrict__ x,
                                                  const float* __restrict__ w,
                                                  f16* __restrict__ Ag,
                                                  f16* __restrict__ Bt) {
  __shared__ float xs[256 * 33];
  const int b = blockIdx.x, t = threadIdx.x;
  const bool isx = (b < M_DIM);
  const float* src0 = isx ? (x + (size_t)b * 8192)
                          : (w + (size_t)(b - M_DIM) * 8192);
  const float4* src = (const float4*)src0;
#pragma unroll
  for (int c = t; c < 2048; c += 256) {      // fully coalesced 16B loads
    float4 v = src[c];
    float* d = xs + (c >> 3) * 33 + ((c & 7) << 2);
    d[0] = v.x; d[1] = v.y; d[2] = v.z; d[3] = v.w;
  }
  __syncthreads();
  const float* xv = xs + t * 33;             // bank = (t+e)%32: conflict-free
  float sv[32];
#pragma unroll
  for (int s = 0; s < 32; ++s)
    sv[s] = (float)HT.f_sgn[s][0] * xv[HT.f_idx[s][0]]
          + (float)HT.f_sgn[s][1] * xv[HT.f_idx[s][1]]
          + (float)HT.f_sgn[s][2] * xv[HT.f_idx[s][2]]
          + (float)HT.f_sgn[s][3] * xv[HT.f_idx[s][3]];
  if (isx) {
#pragma unroll
    for (int c = 0; c < 4; ++c) {
      f16x8 h;
#pragma unroll
      for (int e = 0; e < 8; ++e) {   // e = tt*2+p -> slot tt*8+c*2+p
        int tt = e >> 1, p = e & 1;
        h[e] = (f16)sv[tt * 8 + c * 2 + p];
      }
      *(f16x8*)(Ag + ((size_t)(b * 4 + c)) * K2 + t * 8) = h;
    }
  } else {
    const int o = b - M_DIM;
#pragma unroll
    for (int r = 0; r < 4; ++r)
#pragma unroll
      for (int q = 0; q < 2; ++q) {
        f16x8 h;
#pragma unroll
        for (int e = 0; e < 8; ++e) {
          int tt = e >> 1, p = e & 1;
          float re = sv[(r * 4 + tt) * 2], im = sv[(r * 4 + tt) * 2 + 1];
          float v = (q == 0) ? (p == 0 ? re : -im) : (p == 0 ? im : re);
          h[e] = (f16)v;
        }
        *(f16x8*)(Bt + ((size_t)(o * 8 + r * 2 + q)) * K2 + t * 8) = h;
      }
  }
}

// ---- fused GEMM + inverse transform + normalize ----
// R7: frag reads SOFTWARE-PIPELINED ONE PHASE AHEAD (the m201 ingredient all
// prior rounds missed). Phase p's ds_reads fetch phase p+1's operands, so the
// reads are in flight across a barrier+MFMA window and the LDS pipe streams
// CONTINUOUSLY under the MFMA pipe instead of serially in front of it.
// Quadrant order Q0(avL,bvL) Q1(avL,bvH) Q2(avH,bvL) Q3(avH,bvH): every
// operand's rewrite lands exactly one phase after its last use -> single-
// buffered frags, no dynamic indexing.
//   p0: read bvH(u)[bo]                                ; BAR ; MFMA Q0
//   p1: read avH(u)[bo]                    ; vmcnt(4)  ; BAR ; MFMA Q1
//   p2: read avL(u+1)[nbo] ; stage A->bo   ; vmcnt(4)  ; BAR ; MFMA Q2
//   p3: read bvL(u+1)[nbo] ; stage B->bo               ; BAR ; MFMA Q3
// Stages at u.p2/p3 write bo for tile u+2 (bo's last read was u.p1, barrier-
// separated); invariant 8 outstanding -> vmcnt(4) gates {A,B}(nbo) landed
// BEFORE the barrier preceding the consuming reads (cross-wave sound).
// Prefetch slack: 4 phases (~2400cyc) >> HBM 900. Never vmcnt(0) mid-loop.
__global__ __launch_bounds__(512, 2) void gemm_fused_kernel(const f16* __restrict__ A,
                                                            const f16* __restrict__ Bw,
                                                            float* __restrict__ out) {
  __shared__ __align__(16) char smem[131072];   // 2 bufs x (A 32K + B 32K)
  const int t = threadIdx.x;
  const int w = t >> 6, lane = t & 63;
  const int wr = w >> 2, wc = w & 3;            // 2x4 wave grid
  const int g = lane >> 4, lc = lane & 15;

  // XCD-aware swizzle: 256 blocks, 8 XCDs, 32-block contiguous chunk each
  const int bid = blockIdx.x;
  const int swzb = (bid & 7) * 32 + (bid >> 3);
  const int by = swzb >> 3, bx = swzb & 7;
  const int m0 = by * BM, n0 = bx * BN;

  // staging: load j covers rows j*64 + w*8 + (lane>>3); stored chunk lane&7
  // holds global chunk (lane&7)^(row&7); LDS dest linear (global_load_lds).
  const int srow = lane >> 3;
  const int schk = (lane & 7) ^ srow;
  const f16* ga0 = A  + (size_t)(m0 + w * 8 + srow) * K2 + schk * 8;
  const f16* gb0 = Bw + (size_t)(n0 + w * 8 + srow) * K2 + schk * 8;
  const int lw = w << 10;                       // wave LDS byte base in j-block

  // frag-read offsets: addr = base + row*128 + ((k2*4+g)^(lc&7))*16
  const int cks0 = (g ^ (lc & 7)) << 4;
  const int cks1 = ((4 | g) ^ (lc & 7)) << 4;
  const int arow = (wr << 14) + (lc << 7);            // A region
  const int brow = 32768 + (wc << 13) + (lc << 7);    // B region

  f32x4 acc[8][4];
#pragma unroll
  for (int i = 0; i < 8; ++i)
#pragma unroll
    for (int j = 0; j < 4; ++j) {
      acc[i][j][0] = 0.f; acc[i][j][1] = 0.f; acc[i][j][2] = 0.f; acc[i][j][3] = 0.f;
    }

  // single-buffered fragment sets (rotation is by phase position, not parity)
  f16x8 avL[4][2], avH[4][2], bvL[2][2], bvH[2][2];

#define STG_A(BO, KK, JB) async16(ga0 + (KK) + (JB) * 131072, \
                                  (f16*)(smem + (BO) + (JB) * 8192 + lw))
#define STG_B(BO, KK, JB) async16(gb0 + (KK) + (JB) * 131072, \
                                  (f16*)(smem + (BO) + 32768 + (JB) * 8192 + lw))

#define MFMA_Q(AV, BV, IO, JO) do {                                      \
    __builtin_amdgcn_s_setprio(1);                                       \
    _Pragma("unroll")                                                    \
    for (int k2 = 0; k2 < 2; ++k2)                                       \
      _Pragma("unroll")                                                  \
      for (int i = 0; i < 4; ++i)                                        \
        _Pragma("unroll")                                                \
        for (int j = 0; j < 2; ++j)                                      \
          acc[(IO) + i][(JO) + j] = __builtin_amdgcn_mfma_f32_16x16x32_f16( \
              AV[i][k2], BV[j][k2], acc[(IO) + i][(JO) + j], 0, 0, 0);   \
    __builtin_amdgcn_s_setprio(0);                                       \
  } while (0)

  // prologue: stage tile 0 (A then B) into buf0, tile 1 (A then B) into buf1
  STG_A(0, 0, 0);     STG_A(0, 0, 1);     STG_A(0, 0, 2);     STG_A(0, 0, 3);
  STG_B(0, 0, 0);     STG_B(0, 0, 1);     STG_B(0, 0, 2);     STG_B(0, 0, 3);
  STG_A(65536, BK, 0); STG_A(65536, BK, 1); STG_A(65536, BK, 2); STG_A(65536, BK, 3);
  STG_B(65536, BK, 0); STG_B(65536, BK, 1); STG_B(65536, BK, 2); STG_B(65536, BK, 3);
  WAIT_VM(8);          // tile 0's A+B landed (8 oldest of 16)
  BARRIER();

  {                    // pre-read avL(0), bvL(0) from buf0
    const char* ab = smem + arow;
    const char* bb = smem + brow;
#pragma unroll
    for (int i = 0; i < 4; ++i) {
      avL[i][0] = *(const f16x8*)(ab + i * 2048 + cks0);
      avL[i][1] = *(const f16x8*)(ab + i * 2048 + cks1);
    }
#pragma unroll
    for (int j = 0; j < 2; ++j) {
      bvL[j][0] = *(const f16x8*)(bb + j * 2048 + cks0);
      bvL[j][1] = *(const f16x8*)(bb + j * 2048 + cks1);
    }
  }

  for (int u = 0; u < NT; ++u) {
    const int bo  = (u & 1) << 16;
    const int nbo = bo ^ 65536;
    const int kn  = (u + 2) * BK;       // stage target K for tile u+2
    const char* ab  = smem + bo + arow;
    const char* bb  = smem + bo + brow;
    const char* nab = smem + nbo + arow;
    const char* nbb = smem + nbo + brow;
    const bool rd_nxt = (u + 1 < NT);
    const bool stg    = (u + 2 < NT);

    // ---- p0: read bvH(u); MFMA Q0(avL,bvL) ----
#pragma unroll
    for (int j = 0; j < 2; ++j) {
      bvH[j][0] = *(const f16x8*)(bb + (2 + j) * 2048 + cks0);
      bvH[j][1] = *(const f16x8*)(bb + (2 + j) * 2048 + cks1);
    }
    BARRIER();
    MFMA_Q(avL, bvL, 0, 0);

    // ---- p1: read avH(u); vmcnt gates A(nbo); MFMA Q1(avL,bvH) ----
#pragma unroll
    for (int i = 0; i < 4; ++i) {
      avH[i][0] = *(const f16x8*)(ab + (4 + i) * 2048 + cks0);
      avH[i][1] = *(const f16x8*)(ab + (4 + i) * 2048 + cks1);
    }
    if (u + 1 < NT) WAIT_VM(4);        // A(nbo) landed (outstanding 8)
    BARRIER();
    MFMA_Q(avL, bvH, 0, 2);

    // ---- p2: read avL(u+1) from nbo; stage A->bo; vmcnt gates B(nbo);
    //          MFMA Q2(avH,bvL) ----
    if (rd_nxt) {
#pragma unroll
      for (int i = 0; i < 4; ++i) {
        avL[i][0] = *(const f16x8*)(nab + i * 2048 + cks0);
        avL[i][1] = *(const f16x8*)(nab + i * 2048 + cks1);
      }
    }
    if (stg) { STG_A(bo, kn, 0); STG_A(bo, kn, 1);
               STG_A(bo, kn, 2); STG_A(bo, kn, 3); }
    if (stg)         WAIT_VM(4);       // B(nbo) landed (outstanding 8)
    else if (rd_nxt) WAIT_VM(0);       // tail (u==NT-2): only 4 outstanding
    BARRIER();
    MFMA_Q(avH, bvL, 4, 0);

    // ---- p3: read bvL(u+1) from nbo; stage B->bo; MFMA Q3(avH,bvH) ----
    if (rd_nxt) {
#pragma unroll
      for (int j = 0; j < 2; ++j) {
        bvL[j][0] = *(const f16x8*)(nbb + j * 2048 + cks0);
        bvL[j][1] = *(const f16x8*)(nbb + j * 2048 + cks1);
      }
    }
    if (stg) { STG_B(bo, kn, 0); STG_B(bo, kn, 1);
               STG_B(bo, kn, 2); STG_B(bo, kn, 3); }
    BARRIER();
    MFMA_Q(avH, bvH, 4, 2);
  }

#undef MFMA_Q
#undef STG_B
#undef STG_A

  // ---- epilogue: four 64-row quarters through 66.5 KB of the (free) LDS ----
  // C cell: A-row = wr*128 + tm*16 + g*4 + r ; col = wc*64 + tn*16 + lc
  float* ps = (float*)smem;
  __syncthreads();
#pragma unroll
  for (int qq = 0; qq < 4; ++qq) {
    if (qq) __syncthreads();
    if (wr == (qq >> 1)) {
      const int tb = (qq & 1) << 2;
#pragma unroll
      for (int tmi = 0; tmi < 4; ++tmi) {
        const int rowl = tmi * 16 + g * 4;
#pragma unroll
        for (int tn = 0; tn < 4; ++tn) {
          const int col = wc * 64 + tn * 16 + lc;
#pragma unroll
          for (int r = 0; r < 4; ++r)
            ps[(rowl + r) * PSTR + col] = acc[tb + tmi][tn][r];
        }
      }
    }
    __syncthreads();

    // 512 threads process 16 m-groups x 32 o-groups of this quarter
    const int mh = t >> 5, oh = t & 31;
    float yv[4][8];
#pragma unroll
    for (int c = 0; c < 4; ++c) {
      const float* row = ps + (mh * 4 + c) * PSTR + oh * 8;
      *(float4*)&yv[c][0] = *(const float4*)row;
      *(float4*)&yv[c][4] = *(const float4*)(row + 4);
    }
    float ss = 0.f;
#pragma unroll
    for (int c = 0; c < 4; ++c)
#pragma unroll
      for (int j = 0; j < 8; ++j) ss += yv[c][j] * yv[c][j];
    float inv = rsqrtf(0.25f * ss + 1e-6f);

    float ov[32];
#pragma unroll
    for (int k = 0; k < 32; ++k) {
      float v = 0.f;
#pragma unroll
      for (int j = 0; j < 4; ++j) {
        int s = HT.g_idx[k][j];       // compile-time constant after unroll
        int cell = s >> 1;
        int rr = cell >> 2, cc = cell & 3, pp = s & 1;
        float sgn = (float)HT.g_sgn[k][j];
        v += sgn * yv[cc][rr * 2 + pp];
      }
      ov[k] = v * 0.25f * inv;
    }
    int m = by * 64 + qq * 16 + mh;   // global multivector row
    int o = bx * 32 + oh;             // global output channel
    float* op = out + (size_t)m * 8192 + o * 32;
#pragma unroll
    for (int qv = 0; qv < 8; ++qv)
      *(float4*)(op + qv * 4) = make_float4(ov[qv * 4], ov[qv * 4 + 1],
                                            ov[qv * 4 + 2], ov[qv * 4 + 3]);
  }
}

// ---- safety-net fallback (ws too small): straight fp32 ----
__global__ __launch_bounds__(256) void naive_vl_kernel(const float* __restrict__ x,
                                                       const float* __restrict__ w,
                                                       float* __restrict__ out) {
  __shared__ float xs[8192];
  __shared__ float sgt[1024];
  int m = blockIdx.x, o0 = blockIdx.y << 3;
  int t = threadIdx.x;
  for (int i = t; i < 1024; i += 256) {
    int kk = i >> 5, ll = i & 31;
    sgt[i] = gp_sign_rt(kk ^ ll, ll);
  }
  const float4* xr = (const float4*)(x + (size_t)m * K_FULL);
  float4* xs4 = (float4*)xs;
  for (int i = t; i < 2048; i += 256) xs4[i] = xr[i];
  __syncthreads();
  int k = t & 31, ol = t >> 5;
  int o = o0 + ol;
  const float* wrow = w + (size_t)o * K_FULL;
  float acc = 0.f;
  for (int l = 0; l < 32; ++l) {
    float s = sgt[(k << 5) + l];
    const float* wp = wrow + (k ^ l);
    const float* xp = xs + l;
    float part = 0.f;
#pragma unroll 8
    for (int i = 0; i < 256; ++i) part += xp[i << 5] * wp[i << 5];
    acc += part * s;
  }
  float ss = acc * acc;
  for (int msk = 1; msk < 32; msk <<= 1) ss += __shfl_xor(ss, msk, 32);
  out[((size_t)m * 256 + o) * 32 + k] = acc * rsqrtf(ss + 1e-6f);
}

extern "C" void kernel_launch(void* const* d_in, const int* in_sizes, int n_in,
                              void* d_out, int out_size, void* d_ws, size_t ws_size,
                              hipStream_t stream) {
  const float* x = (const float*)d_in[0];
  const float* w = (const float*)d_in[1];
  float* out = (float*)d_out;

  size_t agE = (size_t)M2 * K2;        // 16.8M f16 = 33.5 MB
  size_t btE = (size_t)N2 * K2;        // 4.2M  f16 =  8.4 MB
  size_t need = (agE + btE) * sizeof(f16);  // ~42 MB

  if (ws_size >= need) {
    f16* Ag = (f16*)d_ws;
    f16* Bt = Ag + agE;
    fwd_kernel<<<dim3(M_DIM + 256), dim3(256), 0, stream>>>(x, w, Ag, Bt);
    gemm_fused_kernel<<<dim3((M2 / BM) * (N2 / BN)), dim3(512), 0, stream>>>(Ag, Bt, out);
  } else {
    naive_vl_kernel<<<dim3(M_DIM, 32), dim3(256), 0, stream>>>(x, w, out);
  }
}